// Round 1
// 70.863 us; speedup vs baseline: 1.0218x; 1.0218x over previous
//
#include <hip/hip_runtime.h>

// Problem: N=4096 rows, F=256 features, H=4 heads.
// Softmax identity: softmax_j(s_i[i,h] + s_j[j,h] + b[h]) == softmax_j(s_j[j,h])
// => attention weights independent of i; output is ONE length-F vector broadcast
// to all N rows:
//   v[f] = (1/H) * sum_h ( sum_j exp(s_j[j,h]) * x[j,f] ) / ( sum_j exp(s_j[j,h]) )
//   out[i,f] = leaky_relu(v[f], 0.2)
//
// This revision: NO atomics, NO hipMemsetAsync -> 2 dispatches instead of
// 3 dispatches + fill node. k1 writes per-block partials (deterministic),
// k2 reduces them from L2 and broadcast-writes the output.

#define NROWS 4096
#define FDIM  256
#define HH    4
#define RPB   32            // rows per block in k1
#define NB1   (NROWS / RPB) // 128 k1 blocks
#define PADF  260           // padded row stride in floats: 1040B, 16B-aligned, banks shift by 4/row
#define RPB2  32            // rows per block in k2
#define NB2   (NROWS / RPB2)// 128 k2 blocks

// ws layout: u_part[NB1][HH][FDIM] (512 KB), then z_part[NB1][HH] (2 KB). No zeroing needed.

__global__ __launch_bounds__(256) void k1_part(const float* __restrict__ x,
                                               const float* __restrict__ W,
                                               float* __restrict__ u_part,
                                               float* __restrict__ z_part) {
    __shared__ __align__(16) float x_lds[RPB * PADF];   // 33.3 KB
    __shared__ __align__(16) float w_lds[HH * PADF];    // 4.2 KB, [h][c] padded
    __shared__ __align__(16) float e_lds[RPB * HH];     // e[r][h]

    const int t = threadIdx.x;
    const int b = blockIdx.x;
    const int row0 = b * RPB;

    // Stage W2 (= W[:, F:2F], row stride 2F=512 floats = 128 float4) as [h][c].
    {
        int h = t >> 6, c4 = t & 63;
        float4 wv = ((const float4*)W)[(size_t)h * (2 * FDIM / 4) + (FDIM / 4) + c4];
        *(float4*)&w_lds[h * PADF + c4 * 4] = wv;
    }
    // Stage 32 x-rows: 32*64 = 2048 float4 -> 8 per thread, coalesced.
    for (int i = t; i < RPB * (FDIM / 4); i += 256) {
        int r = i >> 6, c4 = i & 63;
        float4 v = ((const float4*)x)[(size_t)(row0 + r) * (FDIM / 4) + c4];
        *(float4*)&x_lds[r * PADF + c4 * 4] = v;
    }
    __syncthreads();

    // Phase 1: scores. thread -> (row r, head h, half) ; each computes a 128-feature
    // half-dot with float4 LDS reads, then pairs reduce via shfl_xor(1).
    // Banks: x addr (4r + 0*half)%32 -> 8 distinct banks x 2-way (free);
    //        w addr (4h)%32 -> broadcast groups, 2-way (free).
    {
        int r = t >> 3, h = (t >> 1) & 3, half = t & 1;
        const float4* xr = (const float4*)&x_lds[r * PADF];
        const float4* wr = (const float4*)&w_lds[h * PADF];
        float acc = 0.f;
        #pragma unroll
        for (int i = 0; i < 32; ++i) {
            float4 a = xr[half * 32 + i];
            float4 w = wr[half * 32 + i];
            acc = fmaf(a.x, w.x, acc); acc = fmaf(a.y, w.y, acc);
            acc = fmaf(a.z, w.z, acc); acc = fmaf(a.w, w.w, acc);
        }
        acc += __shfl_xor(acc, 1);
        if (half == 0) e_lds[r * 4 + h] = __expf(acc);  // |s| < ~3: no max-shift needed
    }
    __syncthreads();

    // Per-block softmax-denominator partials (plain store, no atomic).
    if (t < HH) {
        float z = 0.f;
        #pragma unroll
        for (int r = 0; r < RPB; ++r) z += e_lds[r * 4 + t];
        z_part[b * HH + t] = z;
    }

    // Phase 2: per-block partial of u[h][f] = sum_j e[h,j]*x[j,f];  f = t.
    float a0 = 0.f, a1 = 0.f, a2 = 0.f, a3 = 0.f;
    #pragma unroll 8
    for (int r = 0; r < RPB; ++r) {
        float xv = x_lds[r * PADF + t];
        float4 e4 = *(const float4*)&e_lds[r * 4];   // same addr all lanes: broadcast
        a0 = fmaf(e4.x, xv, a0);
        a1 = fmaf(e4.y, xv, a1);
        a2 = fmaf(e4.z, xv, a2);
        a3 = fmaf(e4.w, xv, a3);
    }
    float* up = u_part + (size_t)b * (HH * FDIM);
    up[0 * FDIM + t] = a0;
    up[1 * FDIM + t] = a1;
    up[2 * FDIM + t] = a2;
    up[3 * FDIM + t] = a3;
}

// K2: reduce partials (L2-resident, 512 KB), finalize v, leaky_relu,
// broadcast-write 32 rows per block.
__global__ __launch_bounds__(256) void k2_out(const float* __restrict__ u_part,
                                              const float* __restrict__ z_part,
                                              float* __restrict__ out) {
    __shared__ __align__(16) float v_lds[FDIM];
    __shared__ float z_lds[NB1 * HH];   // 512 floats
    __shared__ float z_fin[HH];
    const int t = threadIdx.x;

    // Stage all z partials, then 4 threads finish the per-head sums.
    z_lds[t]       = z_part[t];
    z_lds[t + 256] = z_part[t + 256];
    __syncthreads();
    if (t < HH) {
        float z = 0.f;
        for (int bb = 0; bb < NB1; ++bb) z += z_lds[bb * 4 + t];
        z_fin[t] = z;
    }

    // Reduce u partials: thread t owns column f=t for all 4 heads.
    // 128 blocks x 4 coalesced 1KB loads; hides z_fin latency.
    float a0 = 0.f, a1 = 0.f, a2 = 0.f, a3 = 0.f;
    for (int bb = 0; bb < NB1; ++bb) {
        const float* up = u_part + (size_t)bb * (HH * FDIM);
        a0 += up[0 * FDIM + t];
        a1 += up[1 * FDIM + t];
        a2 += up[2 * FDIM + t];
        a3 += up[3 * FDIM + t];
    }
    __syncthreads();   // z_fin ready
    float val = 0.25f * (a0 / z_fin[0] + a1 / z_fin[1] + a2 / z_fin[2] + a3 / z_fin[3]);
    v_lds[t] = val > 0.f ? val : 0.2f * val;
    __syncthreads();

    const int row0 = blockIdx.x * RPB2;
    const int c4 = t & 63;          // float4 column 0..63
    const int sub = t >> 6;         // 0..3, each handles 8 rows
    float4 v4 = *(const float4*)&v_lds[c4 * 4];
    float4* out4 = (float4*)out;
    #pragma unroll
    for (int k = 0; k < RPB2 / 4; ++k)
        out4[(size_t)(row0 + sub * (RPB2 / 4) + k) * (FDIM / 4) + c4] = v4;
}

extern "C" void kernel_launch(void* const* d_in, const int* in_sizes, int n_in,
                              void* d_out, int out_size, void* d_ws, size_t ws_size,
                              hipStream_t stream) {
    const float* x = (const float*)d_in[0];   // (4096, 256)
    const float* W = (const float*)d_in[1];   // (4, 512)
    // d_in[2] = b is unused: it cancels in the softmax.
    float* u_part = (float*)d_ws;                       // NB1*HH*FDIM = 128K floats
    float* z_part = u_part + (size_t)NB1 * HH * FDIM;   // NB1*HH = 512 floats
    float* out = (float*)d_out;

    k1_part<<<NB1, 256, 0, stream>>>(x, W, u_part, z_part);
    k2_out<<<NB2, 256, 0, stream>>>(u_part, z_part, out);
}